// Round 1
// baseline (1222.845 us; speedup 1.0000x reference)
//
#include <hip/hip_runtime.h>
#include <stdint.h>

#define TT 4
#define BB 8192
#define DD 128
#define HH 8
#define DHD 1024
#define BD (BB*DD)       // 1048576
#define TBM (TT*BB)      // 32768

// ---------------- Kernel 1: shortcut LIF over x -> xs (u8 spikes) ----------------
__global__ __launch_bounds__(256) void k_lif_x(const float* __restrict__ x,
                                               uint8_t* __restrict__ xs) {
  int i = blockIdx.x * 256 + threadIdx.x;    // over B*D, grid covers exactly
  float v = 0.f;
#pragma unroll
  for (int t = 0; t < TT; t++) {
    float xv = x[(size_t)t * BD + i];
    v = v + (xv - v) * 0.5f;                 // matches np: v + (x-v)/2 (mult by 0.5 exact)
    uint8_t s = (v >= 1.0f) ? (uint8_t)1 : (uint8_t)0;
    xs[(size_t)t * BD + i] = s;
    if (s) v = 0.f;
  }
}

// ---------------- Kernel 2: fused q/k/v GEMM + BN + LIF + kv + kv-LIF + a ----------------
// block: 256 thr; tile: 32 b-rows x 64 dh-cols, all T=4 in registers.
// lane (tx&63) = dh column; grp (tx>>6) = 8-row group of b.
__global__ __launch_bounds__(256) void k_qkv(
    const uint8_t* __restrict__ xs,
    const float* __restrict__ Wq, const float* __restrict__ Wk, const float* __restrict__ Wv,
    const float* __restrict__ bq, const float* __restrict__ gq, const float* __restrict__ betq,
    const float* __restrict__ mq, const float* __restrict__ vq,
    const float* __restrict__ bk, const float* __restrict__ gk, const float* __restrict__ betk,
    const float* __restrict__ mk, const float* __restrict__ vk,
    const float* __restrict__ bv, const float* __restrict__ gv, const float* __restrict__ betv,
    const float* __restrict__ mv, const float* __restrict__ vv_,
    float* __restrict__ vout,          // d_out + T*B*D  (v spikes, f32)
    uint8_t* __restrict__ a_bytes)     // [T*B][128] bit-packed a (column m = h*128+d)
{
  __shared__ uint8_t xs_s[TT * 32 * DD];   // 16 KB  [t][bl][kk]
  __shared__ float W_s[DD][65];            // 33.3 KB, [kk][n] padded -> conflict-free

  const int tx = threadIdx.x;
  const int b0 = blockIdx.x * 32;
  const int dh0 = blockIdx.y * 64;
  const int lane = tx & 63;
  const int grp = tx >> 6;

  // load xs tile (contiguous u32 per t)
  {
    const uint32_t* g = (const uint32_t*)xs;
    uint32_t* s = (uint32_t*)xs_s;
#pragma unroll
    for (int j = 0; j < 16; j++) {
      int f = tx + j * 256;                // 0..4095 u32s
      int t = f >> 10, r = f & 1023;
      s[f] = g[((size_t)t * BD + (size_t)b0 * DD) / 4 + r];
    }
  }

  const int dh = dh0 + lane;

  auto branch = [&](const float* __restrict__ Wg, const float* __restrict__ bb,
                    const float* __restrict__ gg, const float* __restrict__ be,
                    const float* __restrict__ mmp, const float* __restrict__ vvp) -> uint32_t {
    __syncthreads();                       // protect W_s reuse + xs_s initial fill
#pragma unroll
    for (int j = 0; j < 32; j++) {
      int f = tx + j * 256;                // 0..8191
      int n = f >> 7, kk = f & 127;
      W_s[kk][n] = Wg[(size_t)(dh0 + n) * DD + kk];
    }
    __syncthreads();

    float acc[TT][8];
#pragma unroll
    for (int t = 0; t < TT; t++)
#pragma unroll
      for (int bi = 0; bi < 8; bi++) acc[t][bi] = 0.f;

    const uint32_t* xs4 = (const uint32_t*)xs_s;
    for (int k4 = 0; k4 < 32; k4++) {
      float w0 = W_s[k4 * 4 + 0][lane];
      float w1 = W_s[k4 * 4 + 1][lane];
      float w2 = W_s[k4 * 4 + 2][lane];
      float w3 = W_s[k4 * 4 + 3][lane];
#pragma unroll
      for (int t = 0; t < TT; t++) {
#pragma unroll
        for (int bi = 0; bi < 8; bi++) {
          uint32_t xw = xs4[t * 1024 + (grp * 8 + bi) * 32 + k4];
          float a0 = (float)(xw & 0xffu);
          float a1 = (float)((xw >> 8) & 0xffu);
          float a2 = (float)((xw >> 16) & 0xffu);
          float a3 = (float)(xw >> 24);
          acc[t][bi] += a0 * w0;
          acc[t][bi] += a1 * w1;
          acc[t][bi] += a2 * w2;
          acc[t][bi] += a3 * w3;
        }
      }
    }

    // BN (np op order) + LIF over t
    float bias = bb[dh];
    float sc = gg[dh] / sqrtf(vvp[dh] + 1e-5f);
    float mmv = mmp[dh];
    float bev = be[dh];
    uint32_t bits = 0;
#pragma unroll
    for (int bi = 0; bi < 8; bi++) {
      float u = 0.f;
#pragma unroll
      for (int t = 0; t < TT; t++) {
        float y = __fadd_rn(acc[t][bi], bias);
        y = __fadd_rn(__fmul_rn(__fsub_rn(y, mmv), sc), bev);
        u = __fadd_rn(u, __fmul_rn(__fsub_rn(y, u), 0.5f));
        if (u >= 1.0f) { bits |= (1u << (t * 8 + bi)); u = 0.f; }
      }
    }
    return bits;
  };

  uint32_t qb = branch(Wq, bq, gq, betq, mq, vq);
  uint32_t kb = branch(Wk, bk, gk, betk, mk, vk);
  uint32_t vb = branch(Wv, bv, gv, betv, mv, vv_);

  // write v spikes: v[t,b,h,d], dh = d*8+h
  const int hh2 = lane & 7;
  const int dg = (dh0 >> 3) + (lane >> 3);
#pragma unroll
  for (int t = 0; t < TT; t++) {
#pragma unroll
    for (int bi = 0; bi < 8; bi++) {
      float s = (float)((vb >> (t * 8 + bi)) & 1u);
      vout[(((size_t)t * BB + (b0 + grp * 8 + bi)) * HH + hh2) * DD + dg] = s;
    }
  }

  // kv = sum over 8 heads (8 consecutive lanes = one d), LIF(0.5), a = q & kv_s
  uint32_t kvand = kb & vb;
  uint32_t ab = 0;
#pragma unroll
  for (int bi = 0; bi < 8; bi++) {
    float u = 0.f;
#pragma unroll
    for (int t = 0; t < TT; t++) {
      float kvf = (float)((kvand >> (t * 8 + bi)) & 1u);
      kvf += __shfl_xor(kvf, 1);
      kvf += __shfl_xor(kvf, 2);
      kvf += __shfl_xor(kvf, 4);
      u = u + (kvf - u) * 0.5f;            // exact dyadic arithmetic
      uint32_t s = (u >= 0.5f) ? 1u : 0u;
      if (s) u = 0.f;
      uint32_t qbit = (qb >> (t * 8 + bi)) & 1u;
      ab |= (qbit & s) << (t * 8 + bi);
    }
  }

  // pack a bits: column m = h*128 + d; per (t,b) this block owns bytes h*16+blockIdx.y
#pragma unroll
  for (int t = 0; t < TT; t++) {
#pragma unroll
    for (int bi = 0; bi < 8; bi++) {
      unsigned long long msk = __ballot((int)((ab >> (t * 8 + bi)) & 1u));
      if (lane < 8) {
        uint32_t byte = 0;
#pragma unroll
        for (int dd2 = 0; dd2 < 8; dd2++)
          byte |= (uint32_t)((msk >> (dd2 * 8 + lane)) & 1ull) << dd2;
        a_bytes[((size_t)t * BB + (b0 + grp * 8 + bi)) * 128 + lane * 16 + blockIdx.y] =
            (uint8_t)byte;
      }
    }
  }
}

// ---------------- Kernel 3: out = BN(a @ Wp^T + bp) + x ----------------
// block: 256 thr; tile 32 m-rows x 128 j-cols; K=1024 in 16 chunks of 64.
__global__ __launch_bounds__(256) void k_out(
    const uint8_t* __restrict__ a_bytes,
    const float* __restrict__ Wp, const float* __restrict__ bp2,
    const float* __restrict__ gp, const float* __restrict__ betp,
    const float* __restrict__ mp, const float* __restrict__ vp,
    const float* __restrict__ x, float* __restrict__ out)
{
  __shared__ float Wp_s[64][129];   // [kk][j], padded
  __shared__ float a_s[32][64];

  const int tx = threadIdx.x;
  const int m0 = blockIdx.x * 32;
  const int jl = tx & 127;
  const int mg = tx >> 7;

  float acc[16];
#pragma unroll
  for (int i = 0; i < 16; i++) acc[i] = 0.f;

  for (int kc = 0; kc < 16; kc++) {
    __syncthreads();
#pragma unroll
    for (int j = 0; j < 32; j++) {
      int f = tx + j * 256;          // 0..8191
      int jr = f >> 6, kk = f & 63;
      Wp_s[kk][jr] = Wp[(size_t)jr * DHD + kc * 64 + kk];
    }
    if (tx < 64) {
      int row = tx >> 1, iw = tx & 1;
      uint32_t w32 = *(const uint32_t*)&a_bytes[((size_t)(m0 + row)) * 128 + kc * 8 + iw * 4];
#pragma unroll
      for (int j = 0; j < 32; j++)
        a_s[row][iw * 32 + j] = (float)((w32 >> j) & 1u);
    }
    __syncthreads();
    for (int kk = 0; kk < 64; kk++) {
      float w = Wp_s[kk][jl];
#pragma unroll
      for (int mi = 0; mi < 16; mi++)
        acc[mi] += a_s[mg * 16 + mi][kk] * w;
    }
  }

  float scp = gp[jl] / sqrtf(vp[jl] + 1e-5f);
  float bpj = bp2[jl], mpj = mp[jl], bej = betp[jl];
#pragma unroll
  for (int mi = 0; mi < 16; mi++) {
    size_t m = (size_t)m0 + mg * 16 + mi;
    float y = __fadd_rn(acc[mi], bpj);
    y = __fadd_rn(__fmul_rn(__fsub_rn(y, mpj), scp), bej);
    y = __fadd_rn(y, x[m * DD + jl]);
    out[m * DD + jl] = y;
  }
}

// ---------------- launch ----------------
extern "C" void kernel_launch(void* const* d_in, const int* in_sizes, int n_in,
                              void* d_out, int out_size, void* d_ws, size_t ws_size,
                              hipStream_t stream) {
  const float* x    = (const float*)d_in[0];
  const float* Wq   = (const float*)d_in[1];
  const float* Wk   = (const float*)d_in[2];
  const float* Wv   = (const float*)d_in[3];
  const float* Wp   = (const float*)d_in[4];
  const float* bq   = (const float*)d_in[5];
  const float* gq   = (const float*)d_in[6];
  const float* betq = (const float*)d_in[7];
  const float* mq   = (const float*)d_in[8];
  const float* vq   = (const float*)d_in[9];
  const float* bk   = (const float*)d_in[10];
  const float* gk   = (const float*)d_in[11];
  const float* betk = (const float*)d_in[12];
  const float* mk   = (const float*)d_in[13];
  const float* vk   = (const float*)d_in[14];
  const float* bv   = (const float*)d_in[15];
  const float* gv   = (const float*)d_in[16];
  const float* betv = (const float*)d_in[17];
  const float* mv   = (const float*)d_in[18];
  const float* vv   = (const float*)d_in[19];
  const float* bp   = (const float*)d_in[20];
  const float* gp   = (const float*)d_in[21];
  const float* betp = (const float*)d_in[22];
  const float* mp   = (const float*)d_in[23];
  const float* vp   = (const float*)d_in[24];

  float* out  = (float*)d_out;
  float* vout = out + (size_t)TT * BB * DD;

  uint8_t* xs      = (uint8_t*)d_ws;                    // 4,194,304 B
  uint8_t* a_bytes = xs + (size_t)TT * BB * DD;         // 4,194,304 B

  k_lif_x<<<BD / 256, 256, 0, stream>>>(x, xs);

  dim3 g2(BB / 32, DHD / 64);
  k_qkv<<<g2, 256, 0, stream>>>(xs, Wq, Wk, Wv,
                                bq, gq, betq, mq, vq,
                                bk, gk, betk, mk, vk,
                                bv, gv, betv, mv, vv,
                                vout, a_bytes);

  k_out<<<TBM / 32, 256, 0, stream>>>(a_bytes, Wp, bp, gp, betp, mp, vp, x, out);
}

// Round 2
// 559.475 us; speedup vs baseline: 2.1857x; 2.1857x over previous
//
#include <hip/hip_runtime.h>
#include <stdint.h>

#define TT 4
#define BB 8192
#define DD 128
#define HH 8
#define DHD 1024
#define BD (BB*DD)       // 1048576
#define TBM (TT*BB)      // 32768

typedef unsigned long long u64;

// ---------------- Kernel 1: shortcut LIF over x -> bit-packed spike masks ----------------
// One wave per b-row; lane = d and d+64. Mask layout per (t,b): 4 u32 words,
// word w covers k = 32w..32w+31, bit p of word = k offset (ascending).
__global__ __launch_bounds__(256) void k_lif_x(const float* __restrict__ x,
                                               uint32_t* __restrict__ xs_bits) {
  const int wv = threadIdx.x >> 6, lane = threadIdx.x & 63;
  const int b = blockIdx.x * 4 + wv;
  float v0 = 0.f, v1 = 0.f;
#pragma unroll
  for (int t = 0; t < TT; t++) {
    float x0 = x[(size_t)t * BD + (size_t)b * DD + lane];
    float x1 = x[(size_t)t * BD + (size_t)b * DD + 64 + lane];
    v0 = __fadd_rn(v0, __fmul_rn(__fsub_rn(x0, v0), 0.5f));
    v1 = __fadd_rn(v1, __fmul_rn(__fsub_rn(x1, v1), 0.5f));
    int s0 = (v0 >= 1.0f) ? 1 : 0;
    int s1 = (v1 >= 1.0f) ? 1 : 0;
    u64 lo = __ballot(s0);
    u64 hi = __ballot(s1);
    if (s0) v0 = 0.f;
    if (s1) v1 = 0.f;
    if (lane == 0) {
      u64* p = (u64*)&xs_bits[((size_t)t * BB + b) * 4];
      p[0] = lo;   // d 0..63
      p[1] = hi;   // d 64..127
    }
  }
}

// ---------------- Kernel 2: sparse q/k/v GEMM + BN + LIF + kv + kv-LIF + a ----------------
// Block: 256 thr = 4 waves; tile 64 b-rows x 64 dh-cols; wave owns 16 b-rows.
// W staged in LDS as W_s[k][col], col = lane ^ (k>>2) (conflict-free writes AND reads).
// Spike GEMM: per (t,b) chain, scan set bits of the wave-uniform 128-bit mask in
// ascending k, acc += w  (bitwise identical to the dense ascending-k fma chain).
__global__ __launch_bounds__(256) void k_qkv(
    const uint32_t* __restrict__ xs_bits,
    const float* __restrict__ Wq, const float* __restrict__ Wk, const float* __restrict__ Wv,
    const float* __restrict__ bq, const float* __restrict__ gq, const float* __restrict__ betq,
    const float* __restrict__ mq, const float* __restrict__ vq,
    const float* __restrict__ bk, const float* __restrict__ gk, const float* __restrict__ betk,
    const float* __restrict__ mk, const float* __restrict__ vk,
    const float* __restrict__ bv, const float* __restrict__ gv, const float* __restrict__ betv,
    const float* __restrict__ mv, const float* __restrict__ vv_,
    float* __restrict__ vout,          // d_out + T*B*D  (v spikes, f32)
    uint8_t* __restrict__ a_bytes)     // [T*B][128] bit-packed a (bit j = col h*128+d)
{
  __shared__ float W_s[128 * 64];      // 32 KB

  const int tx = threadIdx.x;
  const int b0 = blockIdx.x * 64;
  const int dh0 = blockIdx.y * 64;
  const int lane = tx & 63;
  const int grp = tx >> 6;
  const int dh = dh0 + lane;

  auto lds_w = [&](int kk) -> float {
    return W_s[(kk << 6) | (lane ^ (kk >> 2))];
  };
  // scan set bits of m (k = base+bit ascending), 1-deep pipelined, exact chain order
  auto scan = [&](u64 m, int base, float a) -> float {
    if (m) {
      int k = __builtin_ctzll(m); m &= m - 1;
      float wv = lds_w(base + k);
      while (m) {
        int k2 = __builtin_ctzll(m); m &= m - 1;
        float wn = lds_w(base + k2);
        a = __fadd_rn(a, wv);
        wv = wn;
      }
      a = __fadd_rn(a, wv);
    }
    return a;
  };

  auto branch = [&](const float* __restrict__ Wg, const float* __restrict__ bb,
                    const float* __restrict__ gg, const float* __restrict__ be,
                    const float* __restrict__ mmp, const float* __restrict__ vvp) -> u64 {
    __syncthreads();                   // protect W_s reuse across branches
    {
      const float4* Wg4 = (const float4*)(Wg + (size_t)dh0 * DD);
#pragma unroll
      for (int j = 0; j < 8; j++) {
        int idx = tx + j * 256;        // 0..2047 float4s
        int n = idx >> 5, k4 = idx & 31;
        float4 w = Wg4[n * 32 + k4];   // coalesced: 32 consecutive k4 per row n
        int kk = k4 * 4;
        int col = n ^ k4;              // (kk+i)>>2 == k4 for i<4 -> same col
        W_s[(kk + 0) * 64 + col] = w.x;
        W_s[(kk + 1) * 64 + col] = w.y;
        W_s[(kk + 2) * 64 + col] = w.z;
        W_s[(kk + 3) * 64 + col] = w.w;
      }
    }
    __syncthreads();

    float acc[TT][16];
#pragma unroll
    for (int t = 0; t < TT; t++)
#pragma unroll
      for (int bi = 0; bi < 16; bi++) acc[t][bi] = 0.f;

    const uint4* xb = (const uint4*)xs_bits;
#pragma unroll
    for (int bi = 0; bi < 16; bi++) {
      const int b = b0 + grp * 16 + bi;
#pragma unroll
      for (int t = 0; t < TT; t++) {
        uint4 m4 = xb[(size_t)t * BB + b];     // wave-uniform address
        u64 mlo = ((u64)(uint32_t)__builtin_amdgcn_readfirstlane(m4.y) << 32) |
                  (uint32_t)__builtin_amdgcn_readfirstlane(m4.x);
        u64 mhi = ((u64)(uint32_t)__builtin_amdgcn_readfirstlane(m4.w) << 32) |
                  (uint32_t)__builtin_amdgcn_readfirstlane(m4.z);
        float a = acc[t][bi];
        a = scan(mlo, 0, a);
        a = scan(mhi, 64, a);
        acc[t][bi] = a;
      }
    }

    // BN (np op order) + LIF over t
    float bias = bb[dh];
    float sc = gg[dh] / sqrtf(vvp[dh] + 1e-5f);
    float mmv = mmp[dh];
    float bev = be[dh];
    u64 bits = 0;
#pragma unroll
    for (int bi = 0; bi < 16; bi++) {
      float u = 0.f;
#pragma unroll
      for (int t = 0; t < TT; t++) {
        float y = __fadd_rn(acc[t][bi], bias);
        y = __fadd_rn(__fmul_rn(__fsub_rn(y, mmv), sc), bev);
        u = __fadd_rn(u, __fmul_rn(__fsub_rn(y, u), 0.5f));
        if (u >= 1.0f) { bits |= (1ull << (t * 16 + bi)); u = 0.f; }
      }
    }
    return bits;
  };

  u64 qb = branch(Wq, bq, gq, betq, mq, vq);
  u64 kb = branch(Wk, bk, gk, betk, mk, vk);
  u64 vb = branch(Wv, bv, gv, betv, mv, vv_);

  // write v spikes: v[t,b,h,d], dh = d*8+h
  const int hh2 = lane & 7;
  const int dg = (dh0 >> 3) + (lane >> 3);
#pragma unroll
  for (int t = 0; t < TT; t++) {
#pragma unroll
    for (int bi = 0; bi < 16; bi++) {
      float s = (float)((vb >> (t * 16 + bi)) & 1ull);
      vout[(((size_t)t * BB + (b0 + grp * 16 + bi)) * HH + hh2) * DD + dg] = s;
    }
  }

  // kv = sum over 8 heads (8 consecutive lanes = one d), LIF(0.5), a = q & kv_s
  u64 kvand = kb & vb;
  u64 ab = 0;
#pragma unroll
  for (int bi = 0; bi < 16; bi++) {
    float u = 0.f;
#pragma unroll
    for (int t = 0; t < TT; t++) {
      float kvf = (float)((kvand >> (t * 16 + bi)) & 1ull);
      kvf += __shfl_xor(kvf, 1);
      kvf += __shfl_xor(kvf, 2);
      kvf += __shfl_xor(kvf, 4);
      u = u + (kvf - u) * 0.5f;        // exact dyadic arithmetic
      uint32_t s = (u >= 0.5f) ? 1u : 0u;
      if (s) u = 0.f;
      uint32_t qbit = (uint32_t)((qb >> (t * 16 + bi)) & 1ull);
      ab |= (u64)(qbit & s) << (t * 16 + bi);
    }
  }

  // pack a bits: column j = h*128 + d; byte j>>3 = h*16 + blockIdx.y, bit j&7
#pragma unroll
  for (int t = 0; t < TT; t++) {
#pragma unroll
    for (int bi = 0; bi < 16; bi++) {
      u64 msk = __ballot((int)((ab >> (t * 16 + bi)) & 1ull));
      if (lane < 8) {
        uint32_t byte = 0;
#pragma unroll
        for (int d2 = 0; d2 < 8; d2++)
          byte |= (uint32_t)((msk >> (d2 * 8 + lane)) & 1ull) << d2;
        a_bytes[((size_t)t * BB + (b0 + grp * 16 + bi)) * 128 + lane * 16 + blockIdx.y] =
            (uint8_t)byte;
      }
    }
  }
}

// ---------------- Kernel 3: out = BN(a @ Wp^T + bp) + x  (sparse over a bits) ----------------
// One wave per output row m; lane covers j = lane and lane+64.
__global__ __launch_bounds__(256) void k_out(
    const uint8_t* __restrict__ a_bytes,
    const float* __restrict__ Wp, const float* __restrict__ bp2,
    const float* __restrict__ gp, const float* __restrict__ betp,
    const float* __restrict__ mp, const float* __restrict__ vp,
    const float* __restrict__ x, float* __restrict__ out)
{
  const int wv = threadIdx.x >> 6, lane = threadIdx.x & 63;
  const size_t m = (size_t)blockIdx.x * 4 + wv;

  const uint4* aw = (const uint4*)(a_bytes + m * 128);
  float acc0 = 0.f, acc1 = 0.f;
#pragma unroll
  for (int q4 = 0; q4 < 8; q4++) {
    uint4 mq = aw[q4];
    uint32_t ws[4];
    ws[0] = (uint32_t)__builtin_amdgcn_readfirstlane(mq.x);
    ws[1] = (uint32_t)__builtin_amdgcn_readfirstlane(mq.y);
    ws[2] = (uint32_t)__builtin_amdgcn_readfirstlane(mq.z);
    ws[3] = (uint32_t)__builtin_amdgcn_readfirstlane(mq.w);
#pragma unroll
    for (int w = 0; w < 4; w++) {
      uint32_t mm = ws[w];
      while (mm) {
        int kb = __builtin_ctz(mm); mm &= mm - 1;
        int k = q4 * 128 + w * 32 + kb;
        acc0 = __fadd_rn(acc0, Wp[(size_t)lane * DHD + k]);
        acc1 = __fadd_rn(acc1, Wp[(size_t)(lane + 64) * DHD + k]);
      }
    }
  }

  // BN + residual for j = lane and lane+64
#pragma unroll
  for (int half = 0; half < 2; half++) {
    int j = lane + half * 64;
    float acc = half ? acc1 : acc0;
    float scp = gp[j] / sqrtf(vp[j] + 1e-5f);
    float y = __fadd_rn(acc, bp2[j]);
    y = __fadd_rn(__fmul_rn(__fsub_rn(y, mp[j]), scp), betp[j]);
    y = __fadd_rn(y, x[m * DD + j]);
    out[m * DD + j] = y;
  }
}

// ---------------- launch ----------------
extern "C" void kernel_launch(void* const* d_in, const int* in_sizes, int n_in,
                              void* d_out, int out_size, void* d_ws, size_t ws_size,
                              hipStream_t stream) {
  const float* x    = (const float*)d_in[0];
  const float* Wq   = (const float*)d_in[1];
  const float* Wk   = (const float*)d_in[2];
  const float* Wv   = (const float*)d_in[3];
  const float* Wp   = (const float*)d_in[4];
  const float* bq   = (const float*)d_in[5];
  const float* gq   = (const float*)d_in[6];
  const float* betq = (const float*)d_in[7];
  const float* mq   = (const float*)d_in[8];
  const float* vq   = (const float*)d_in[9];
  const float* bk   = (const float*)d_in[10];
  const float* gk   = (const float*)d_in[11];
  const float* betk = (const float*)d_in[12];
  const float* mk   = (const float*)d_in[13];
  const float* vk   = (const float*)d_in[14];
  const float* bv   = (const float*)d_in[15];
  const float* gv   = (const float*)d_in[16];
  const float* betv = (const float*)d_in[17];
  const float* mv   = (const float*)d_in[18];
  const float* vv   = (const float*)d_in[19];
  const float* bp   = (const float*)d_in[20];
  const float* gp   = (const float*)d_in[21];
  const float* betp = (const float*)d_in[22];
  const float* mp   = (const float*)d_in[23];
  const float* vp   = (const float*)d_in[24];

  float* out  = (float*)d_out;
  float* vout = out + (size_t)TT * BB * DD;

  uint32_t* xs_bits = (uint32_t*)d_ws;                          // 512 KB
  uint8_t*  a_bytes = (uint8_t*)d_ws + (size_t)TBM * 16;        // 4 MB

  k_lif_x<<<BB / 4, 256, 0, stream>>>(x, xs_bits);

  dim3 g2(BB / 64, DHD / 64);
  k_qkv<<<g2, 256, 0, stream>>>(xs_bits, Wq, Wk, Wv,
                                bq, gq, betq, mq, vq,
                                bk, gk, betk, mk, vk,
                                bv, gv, betv, mv, vv,
                                vout, a_bytes);

  k_out<<<TBM / 4, 256, 0, stream>>>(a_bytes, Wp, bp, gp, betp, mp, vp, x, out);
}

// Round 3
// 130.760 us; speedup vs baseline: 9.3518x; 4.2786x over previous
//
#include <hip/hip_runtime.h>
#include <stdint.h>

#define TT 4
#define BB 8192
#define DD 128
#define HH 8
#define DHD 1024
#define BD (BB*DD)       // 1048576
#define TBM (TT*BB)      // 32768
#define VN (TT*BB*HH*DD) // 33554432
#define ON (TT*BB*DD)    // 4194304

typedef unsigned long long u64;
typedef __attribute__((ext_vector_type(8))) short bf16x8;
typedef __attribute__((ext_vector_type(4))) float f32x4;

// ---------------- K1: shortcut LIF over x -> bit-packed spike masks (+flag=0) --------
__global__ __launch_bounds__(256) void k_lif_x(const float* __restrict__ x,
                                               uint32_t* __restrict__ xs_bits,
                                               int* __restrict__ flag) {
  if (blockIdx.x == 0 && threadIdx.x == 0) *flag = 0;
  const int wv = threadIdx.x >> 6, lane = threadIdx.x & 63;
  const int b = blockIdx.x * 4 + wv;
  float v0 = 0.f, v1 = 0.f;
#pragma unroll
  for (int t = 0; t < TT; t++) {
    float x0 = x[(size_t)t * BD + (size_t)b * DD + lane];
    float x1 = x[(size_t)t * BD + (size_t)b * DD + 64 + lane];
    v0 = __fadd_rn(v0, __fmul_rn(__fsub_rn(x0, v0), 0.5f));
    v1 = __fadd_rn(v1, __fmul_rn(__fsub_rn(x1, v1), 0.5f));
    int s0 = (v0 >= 1.0f) ? 1 : 0;
    int s1 = (v1 >= 1.0f) ? 1 : 0;
    u64 lo = __ballot(s0);
    u64 hi = __ballot(s1);
    if (s0) v0 = 0.f;
    if (s1) v1 = 0.f;
    if (lane == 0) {
      u64* p = (u64*)&xs_bits[((size_t)t * BB + b) * 4];
      p[0] = lo;
      p[1] = hi;
    }
  }
}

// ---------------- K2: convert W -> bf16 + per-column rounding-error bound ------------
// Wb: [3][1024][128] u16 bf16; Dcol: [3][1024] = sum_k |W - bf16(W)|
__global__ __launch_bounds__(256) void k_wconv(const float* __restrict__ Wq,
                                               const float* __restrict__ Wk,
                                               const float* __restrict__ Wv,
                                               uint16_t* __restrict__ Wb,
                                               float* __restrict__ Dcol) {
  const int wv = threadIdx.x >> 6, lane = threadIdx.x & 63;
  const int row = blockIdx.x * 4 + wv;          // 0..3071
  const int br = row >> 10, dh = row & 1023;
  const float* W = (br == 0) ? Wq : (br == 1) ? Wk : Wv;
  float d = 0.f;
#pragma unroll
  for (int h = 0; h < 2; h++) {
    int k = lane + 64 * h;
    float w = W[(size_t)dh * DD + k];
    uint32_t bits = __builtin_bit_cast(uint32_t, w);
    uint32_t r = (bits + 0x7fffu + ((bits >> 16) & 1u)) >> 16;   // RNE to bf16
    Wb[(size_t)row * DD + k] = (uint16_t)r;
    float wb = __builtin_bit_cast(float, r << 16);
    d += fabsf(w - wb);
  }
#pragma unroll
  for (int s = 1; s < 64; s <<= 1) d += __shfl_xor(d, s);
  if (lane == 0) Dcol[row] = d;
}

// ---------------- K3: MFMA no-spike certificate --------------------------------------
// Rows reordered m' = b*4 + t so each lane's 4 C-regs = one membrane chain (t=0..3).
// Tile 128x128, K=128, 4 waves (2x2), per-wave 64x64. A shared across 3 branches.
__global__ __launch_bounds__(256) void k_cert(
    const uint32_t* __restrict__ xs_bits,
    const uint16_t* __restrict__ Wb, const float* __restrict__ Dcol,
    const float* __restrict__ bq, const float* __restrict__ gq, const float* __restrict__ betq,
    const float* __restrict__ mq, const float* __restrict__ vq,
    const float* __restrict__ bk, const float* __restrict__ gk, const float* __restrict__ betk,
    const float* __restrict__ mk, const float* __restrict__ vk,
    const float* __restrict__ bv, const float* __restrict__ gv, const float* __restrict__ betv,
    const float* __restrict__ mv, const float* __restrict__ vv_,
    int* __restrict__ flag)
{
  __shared__ short As[128 * 128];   // 32 KB, row r, slot s at [r*128 + (s^(r&15))*8]
  __shared__ short Bs[128 * 128];   // 32 KB, same swizzle by row n

  const int tx = threadIdx.x;
  const int m0 = blockIdx.x * 128;
  const int n0 = blockIdx.y * 128;
  const int lane = tx & 63;
  const int wv = tx >> 6;
  const int wm = wv >> 1, wn = wv & 1;

  // expand A from bits -> bf16 {0, 0x3F80}
  {
    const int r = tx >> 1, h = tx & 1;
    const int rp = m0 + r, b = rp >> 2, t = rp & 3;
    u64 bits = ((const u64*)&xs_bits[((size_t)t * BB + b) * 4])[h];
#pragma unroll
    for (int i = 0; i < 8; i++) {
      int s = h * 8 + i;
      uint32_t by = (uint32_t)(bits >> (8 * i)) & 0xffu;
      bf16x8 vbt;
#pragma unroll
      for (int j = 0; j < 8; j++) vbt[j] = ((by >> j) & 1u) ? (short)0x3F80 : (short)0;
      *(bf16x8*)&As[r * 128 + ((s ^ (r & 15)) * 8)] = vbt;
    }
  }

  bf16x8 afr[4][4];
  bool bad = false;

#pragma unroll
  for (int br = 0; br < 3; br++) {
    // stage B tile (bf16 rows of this branch's W)
    {
      const int r = tx >> 1, h = tx & 1;
      const uint4* src = (const uint4*)(Wb + ((size_t)br * DHD + (n0 + r)) * DD);
#pragma unroll
      for (int i = 0; i < 8; i++) {
        int s = h * 8 + i;
        uint4 w = src[s];
        *(uint4*)&As[0];  // no-op guard against reorder (kept trivial)
        *(uint4*)&Bs[r * 128 + ((s ^ (r & 15)) * 8)] = w;
      }
    }
    __syncthreads();

    if (br == 0) {
#pragma unroll
      for (int mf = 0; mf < 4; mf++)
#pragma unroll
        for (int ks = 0; ks < 4; ks++) {
          int r = wm * 64 + mf * 16 + (lane & 15);
          int s = ks * 4 + (lane >> 4);
          afr[mf][ks] = *(const bf16x8*)&As[r * 128 + ((s ^ (r & 15)) * 8)];
        }
    }

    f32x4 acc[4][4];
#pragma unroll
    for (int mf = 0; mf < 4; mf++)
#pragma unroll
      for (int nf = 0; nf < 4; nf++) acc[mf][nf] = (f32x4){0.f, 0.f, 0.f, 0.f};

#pragma unroll
    for (int ks = 0; ks < 4; ks++) {
      bf16x8 bfr[4];
#pragma unroll
      for (int nf = 0; nf < 4; nf++) {
        int n = wn * 64 + nf * 16 + (lane & 15);
        int s = ks * 4 + (lane >> 4);
        bfr[nf] = *(const bf16x8*)&Bs[n * 128 + ((s ^ (n & 15)) * 8)];
      }
#pragma unroll
      for (int mf = 0; mf < 4; mf++)
#pragma unroll
        for (int nf = 0; nf < 4; nf++)
          acc[mf][nf] = __builtin_amdgcn_mfma_f32_16x16x32_bf16(afr[mf][ks], bfr[nf],
                                                                acc[mf][nf], 0, 0, 0);
    }
    __syncthreads();   // Bs free for next branch

    const float* bb = (br == 0) ? bq : (br == 1) ? bk : bv;
    const float* gg = (br == 0) ? gq : (br == 1) ? gk : gv;
    const float* be = (br == 0) ? betq : (br == 1) ? betk : betv;
    const float* mm = (br == 0) ? mq : (br == 1) ? mk : mv;
    const float* vp2 = (br == 0) ? vq : (br == 1) ? vk : vv_;
    const float* Dc = Dcol + br * DHD;

#pragma unroll
    for (int nf = 0; nf < 4; nf++) {
      int dh = n0 + wn * 64 + nf * 16 + (lane & 15);
      float sc = gg[dh] / sqrtf(vp2[dh] + 1e-5f);
      float c1 = (bb[dh] - mm[dh]) * sc + be[dh];
      float thr = 1.0f - (fabsf(sc) * Dc[dh] + 1e-3f);
#pragma unroll
      for (int mf = 0; mf < 4; mf++) {
        f32x4 a4 = acc[mf][nf];
        float y, u, umax;
        y = fmaf(a4[0], sc, c1); u = y * 0.5f;        umax = u;
        y = fmaf(a4[1], sc, c1); u = (u + y) * 0.5f;  umax = fmaxf(umax, u);
        y = fmaf(a4[2], sc, c1); u = (u + y) * 0.5f;  umax = fmaxf(umax, u);
        y = fmaf(a4[3], sc, c1); u = (u + y) * 0.5f;  umax = fmaxf(umax, u);
        bad |= (umax > thr);
      }
    }
  }

  if (__any((int)bad)) {
    if (lane == 0) atomicOr(flag, 1);
  }
}

// ---------------- K4: finalize when no spikes (flag==0): v=0, out = BN(bp)+x ---------
__global__ __launch_bounds__(256) void k_final(const int* __restrict__ flag,
                                               float* __restrict__ out, const float* __restrict__ x,
                                               const float* __restrict__ bp, const float* __restrict__ gp,
                                               const float* __restrict__ betp, const float* __restrict__ mp,
                                               const float* __restrict__ vp) {
  if (flag[0] != 0) return;
  float* vout = out + ON;
  const int VN4 = VN / 4, TOT4 = (VN + ON) / 4;
  int idx = blockIdx.x * 256 + threadIdx.x;
  int stride = gridDim.x * 256;
  float4 z = {0.f, 0.f, 0.f, 0.f};
  for (int i = idx; i < TOT4; i += stride) {
    if (i < VN4) {
      ((float4*)vout)[i] = z;
    } else {
      int o = i - VN4;
      float4 xv = ((const float4*)x)[o];
      float4 r;
#pragma unroll
      for (int c = 0; c < 4; c++) {
        int j = (o * 4 + c) & 127;
        float sc = gp[j] / sqrtf(vp[j] + 1e-5f);
        float y = __fadd_rn(0.0f, bp[j]);
        y = __fadd_rn(__fmul_rn(__fsub_rn(y, mp[j]), sc), betp[j]);
        ((float*)&r)[c] = __fadd_rn(y, ((const float*)&xv)[c]);
      }
      ((float4*)out)[o] = r;
    }
  }
}

// ---------------- Fallback (flag!=0): bit-exact sparse pipeline from R2 --------------
__global__ __launch_bounds__(256) void k_qkv(
    const uint32_t* __restrict__ xs_bits,
    const float* __restrict__ Wq, const float* __restrict__ Wk, const float* __restrict__ Wv,
    const float* __restrict__ bq, const float* __restrict__ gq, const float* __restrict__ betq,
    const float* __restrict__ mq, const float* __restrict__ vq,
    const float* __restrict__ bk, const float* __restrict__ gk, const float* __restrict__ betk,
    const float* __restrict__ mk, const float* __restrict__ vk,
    const float* __restrict__ bv, const float* __restrict__ gv, const float* __restrict__ betv,
    const float* __restrict__ mv, const float* __restrict__ vv_,
    float* __restrict__ vout, uint8_t* __restrict__ a_bytes,
    const int* __restrict__ flag)
{
  if (flag[0] == 0) return;
  __shared__ float W_s[128 * 64];

  const int tx = threadIdx.x;
  const int b0 = blockIdx.x * 64;
  const int dh0 = blockIdx.y * 64;
  const int lane = tx & 63;
  const int grp = tx >> 6;
  const int dh = dh0 + lane;

  auto lds_w = [&](int kk) -> float {
    return W_s[(kk << 6) | (lane ^ (kk >> 2))];
  };
  auto scan = [&](u64 m, int base, float a) -> float {
    if (m) {
      int k = __builtin_ctzll(m); m &= m - 1;
      float wv = lds_w(base + k);
      while (m) {
        int k2 = __builtin_ctzll(m); m &= m - 1;
        float wn = lds_w(base + k2);
        a = __fadd_rn(a, wv);
        wv = wn;
      }
      a = __fadd_rn(a, wv);
    }
    return a;
  };

  auto branch = [&](const float* __restrict__ Wg, const float* __restrict__ bb,
                    const float* __restrict__ gg, const float* __restrict__ be,
                    const float* __restrict__ mmp, const float* __restrict__ vvp) -> u64 {
    __syncthreads();
    {
      const float4* Wg4 = (const float4*)(Wg + (size_t)dh0 * DD);
#pragma unroll
      for (int j = 0; j < 8; j++) {
        int idx = tx + j * 256;
        int n = idx >> 5, k4 = idx & 31;
        float4 w = Wg4[n * 32 + k4];
        int kk = k4 * 4;
        int col = n ^ k4;
        W_s[(kk + 0) * 64 + col] = w.x;
        W_s[(kk + 1) * 64 + col] = w.y;
        W_s[(kk + 2) * 64 + col] = w.z;
        W_s[(kk + 3) * 64 + col] = w.w;
      }
    }
    __syncthreads();

    float acc[TT][16];
#pragma unroll
    for (int t = 0; t < TT; t++)
#pragma unroll
      for (int bi = 0; bi < 16; bi++) acc[t][bi] = 0.f;

    const uint4* xb = (const uint4*)xs_bits;
#pragma unroll
    for (int bi = 0; bi < 16; bi++) {
      const int b = b0 + grp * 16 + bi;
#pragma unroll
      for (int t = 0; t < TT; t++) {
        uint4 m4 = xb[(size_t)t * BB + b];
        u64 mlo = ((u64)(uint32_t)__builtin_amdgcn_readfirstlane(m4.y) << 32) |
                  (uint32_t)__builtin_amdgcn_readfirstlane(m4.x);
        u64 mhi = ((u64)(uint32_t)__builtin_amdgcn_readfirstlane(m4.w) << 32) |
                  (uint32_t)__builtin_amdgcn_readfirstlane(m4.z);
        float a = acc[t][bi];
        a = scan(mlo, 0, a);
        a = scan(mhi, 64, a);
        acc[t][bi] = a;
      }
    }

    float bias = bb[dh];
    float sc = gg[dh] / sqrtf(vvp[dh] + 1e-5f);
    float mmv = mmp[dh];
    float bev = be[dh];
    u64 bits = 0;
#pragma unroll
    for (int bi = 0; bi < 16; bi++) {
      float u = 0.f;
#pragma unroll
      for (int t = 0; t < TT; t++) {
        float y = __fadd_rn(acc[t][bi], bias);
        y = __fadd_rn(__fmul_rn(__fsub_rn(y, mmv), sc), bev);
        u = __fadd_rn(u, __fmul_rn(__fsub_rn(y, u), 0.5f));
        if (u >= 1.0f) { bits |= (1ull << (t * 16 + bi)); u = 0.f; }
      }
    }
    return bits;
  };

  u64 qb = branch(Wq, bq, gq, betq, mq, vq);
  u64 kb = branch(Wk, bk, gk, betk, mk, vk);
  u64 vb = branch(Wv, bv, gv, betv, mv, vv_);

  const int hh2 = lane & 7;
  const int dg = (dh0 >> 3) + (lane >> 3);
#pragma unroll
  for (int t = 0; t < TT; t++) {
#pragma unroll
    for (int bi = 0; bi < 16; bi++) {
      float s = (float)((vb >> (t * 16 + bi)) & 1ull);
      vout[(((size_t)t * BB + (b0 + grp * 16 + bi)) * HH + hh2) * DD + dg] = s;
    }
  }

  u64 kvand = kb & vb;
  u64 ab = 0;
#pragma unroll
  for (int bi = 0; bi < 16; bi++) {
    float u = 0.f;
#pragma unroll
    for (int t = 0; t < TT; t++) {
      float kvf = (float)((kvand >> (t * 16 + bi)) & 1ull);
      kvf += __shfl_xor(kvf, 1);
      kvf += __shfl_xor(kvf, 2);
      kvf += __shfl_xor(kvf, 4);
      u = u + (kvf - u) * 0.5f;
      uint32_t s = (u >= 0.5f) ? 1u : 0u;
      if (s) u = 0.f;
      uint32_t qbit = (uint32_t)((qb >> (t * 16 + bi)) & 1ull);
      ab |= (u64)(qbit & s) << (t * 16 + bi);
    }
  }

#pragma unroll
  for (int t = 0; t < TT; t++) {
#pragma unroll
    for (int bi = 0; bi < 16; bi++) {
      u64 msk = __ballot((int)((ab >> (t * 16 + bi)) & 1ull));
      if (lane < 8) {
        uint32_t byte = 0;
#pragma unroll
        for (int d2 = 0; d2 < 8; d2++)
          byte |= (uint32_t)((msk >> (d2 * 8 + lane)) & 1ull) << d2;
        a_bytes[((size_t)t * BB + (b0 + grp * 16 + bi)) * 128 + lane * 16 + blockIdx.y] =
            (uint8_t)byte;
      }
    }
  }
}

__global__ __launch_bounds__(256) void k_out(
    const uint8_t* __restrict__ a_bytes,
    const float* __restrict__ Wp, const float* __restrict__ bp2,
    const float* __restrict__ gp, const float* __restrict__ betp,
    const float* __restrict__ mp, const float* __restrict__ vp,
    const float* __restrict__ x, float* __restrict__ out,
    const int* __restrict__ flag)
{
  if (flag[0] == 0) return;
  const int wv = threadIdx.x >> 6, lane = threadIdx.x & 63;
  const size_t m = (size_t)blockIdx.x * 4 + wv;

  const uint4* aw = (const uint4*)(a_bytes + m * 128);
  float acc0 = 0.f, acc1 = 0.f;
#pragma unroll
  for (int q4 = 0; q4 < 8; q4++) {
    uint4 mq = aw[q4];
    uint32_t ws[4];
    ws[0] = (uint32_t)__builtin_amdgcn_readfirstlane(mq.x);
    ws[1] = (uint32_t)__builtin_amdgcn_readfirstlane(mq.y);
    ws[2] = (uint32_t)__builtin_amdgcn_readfirstlane(mq.z);
    ws[3] = (uint32_t)__builtin_amdgcn_readfirstlane(mq.w);
#pragma unroll
    for (int w = 0; w < 4; w++) {
      uint32_t mm = ws[w];
      while (mm) {
        int kb = __builtin_ctz(mm); mm &= mm - 1;
        int k = q4 * 128 + w * 32 + kb;
        acc0 = __fadd_rn(acc0, Wp[(size_t)lane * DHD + k]);
        acc1 = __fadd_rn(acc1, Wp[(size_t)(lane + 64) * DHD + k]);
      }
    }
  }

#pragma unroll
  for (int half = 0; half < 2; half++) {
    int j = lane + half * 64;
    float acc = half ? acc1 : acc0;
    float scp = gp[j] / sqrtf(vp[j] + 1e-5f);
    float y = __fadd_rn(acc, bp2[j]);
    y = __fadd_rn(__fmul_rn(__fsub_rn(y, mp[j]), scp), betp[j]);
    y = __fadd_rn(y, x[m * DD + j]);
    out[m * DD + j] = y;
  }
}

// ---------------- launch ----------------
extern "C" void kernel_launch(void* const* d_in, const int* in_sizes, int n_in,
                              void* d_out, int out_size, void* d_ws, size_t ws_size,
                              hipStream_t stream) {
  const float* x    = (const float*)d_in[0];
  const float* Wq   = (const float*)d_in[1];
  const float* Wk   = (const float*)d_in[2];
  const float* Wv   = (const float*)d_in[3];
  const float* Wp   = (const float*)d_in[4];
  const float* bq   = (const float*)d_in[5];
  const float* gq   = (const float*)d_in[6];
  const float* betq = (const float*)d_in[7];
  const float* mq   = (const float*)d_in[8];
  const float* vq   = (const float*)d_in[9];
  const float* bk   = (const float*)d_in[10];
  const float* gk   = (const float*)d_in[11];
  const float* betk = (const float*)d_in[12];
  const float* mk   = (const float*)d_in[13];
  const float* vk   = (const float*)d_in[14];
  const float* bv   = (const float*)d_in[15];
  const float* gv   = (const float*)d_in[16];
  const float* betv = (const float*)d_in[17];
  const float* mv   = (const float*)d_in[18];
  const float* vv   = (const float*)d_in[19];
  const float* bp   = (const float*)d_in[20];
  const float* gp   = (const float*)d_in[21];
  const float* betp = (const float*)d_in[22];
  const float* mp   = (const float*)d_in[23];
  const float* vp   = (const float*)d_in[24];

  float* out  = (float*)d_out;
  float* vout = out + (size_t)ON;

  uint8_t* ws = (uint8_t*)d_ws;
  uint32_t* xs_bits = (uint32_t*)ws;                        // 512 KB
  uint8_t*  a_bytes = ws + 524288;                          // 4 MB
  uint16_t* Wb      = (uint16_t*)(ws + 4718592);            // 768 KB
  float*    Dcol    = (float*)(ws + 5505024);               // 12 KB
  int*      flag    = (int*)(ws + 5517312);                 // 4 B

  k_lif_x<<<BB / 4, 256, 0, stream>>>(x, xs_bits, flag);
  k_wconv<<<768, 256, 0, stream>>>(Wq, Wk, Wv, Wb, Dcol);

  dim3 gc(TBM / 128, DHD / 128);
  k_cert<<<gc, 256, 0, stream>>>(xs_bits, Wb, Dcol,
                                 bq, gq, betq, mq, vq,
                                 bk, gk, betk, mk, vk,
                                 bv, gv, betv, mv, vv,
                                 flag);

  k_final<<<2048, 256, 0, stream>>>(flag, out, x, bp, gp, betp, mp, vp);

  dim3 g2(BB / 64, DHD / 64);
  k_qkv<<<g2, 256, 0, stream>>>(xs_bits, Wq, Wk, Wv,
                                bq, gq, betq, mq, vq,
                                bk, gk, betk, mk, vk,
                                bv, gv, betv, mv, vv,
                                vout, a_bytes, flag);

  k_out<<<TBM / 4, 256, 0, stream>>>(a_bytes, Wp, bp, gp, betp, mp, vp, x, out, flag);
}

// Round 4
// 93.146 us; speedup vs baseline: 13.1282x; 1.4038x over previous
//
#include <hip/hip_runtime.h>
#include <stdint.h>

#define TT 4
#define BB 8192
#define DD 128
#define HH 8
#define DHD 1024
#define BD (BB*DD)       // 1048576
#define TBM (TT*BB)      // 32768
#define VN (TT*BB*HH*DD) // 33554432
#define ON (TT*BB*DD)    // 4194304

typedef unsigned long long u64;
typedef __attribute__((ext_vector_type(8))) short bf16x8;
typedef __attribute__((ext_vector_type(4))) float f32x4;

__device__ inline uint32_t encf(float f) {   // monotone float->uint for atomicMin/Max
  uint32_t b = __builtin_bit_cast(uint32_t, f);
  return (b & 0x80000000u) ? ~b : (b | 0x80000000u);
}
__device__ inline float decf(uint32_t e) {
  uint32_t b = (e & 0x80000000u) ? (e ^ 0x80000000u) : ~e;
  return __builtin_bit_cast(float, b);
}

// ---------------- K1: shortcut LIF over x -> bit-packed spike masks (+init) ---------
__global__ __launch_bounds__(256) void k_lif_x(const float* __restrict__ x,
                                               uint32_t* __restrict__ xs_bits,
                                               int* __restrict__ flag,
                                               uint32_t* __restrict__ cbuf) {
  if (blockIdx.x == 0 && threadIdx.x == 0) {
    *flag = 0;
    uint32_t ehi = encf(3.0e38f), elo = encf(-3.0e38f);
    cbuf[0] = ehi; cbuf[1] = ehi; cbuf[2] = ehi;
    cbuf[3] = elo; cbuf[4] = elo; cbuf[5] = elo;
  }
  const int wv = threadIdx.x >> 6, lane = threadIdx.x & 63;
  const int b = blockIdx.x * 4 + wv;
  float v0 = 0.f, v1 = 0.f;
#pragma unroll
  for (int t = 0; t < TT; t++) {
    float x0 = x[(size_t)t * BD + (size_t)b * DD + lane];
    float x1 = x[(size_t)t * BD + (size_t)b * DD + 64 + lane];
    v0 = __fadd_rn(v0, __fmul_rn(__fsub_rn(x0, v0), 0.5f));
    v1 = __fadd_rn(v1, __fmul_rn(__fsub_rn(x1, v1), 0.5f));
    int s0 = (v0 >= 1.0f) ? 1 : 0;
    int s1 = (v1 >= 1.0f) ? 1 : 0;
    u64 lo = __ballot(s0);
    u64 hi = __ballot(s1);
    if (s0) v0 = 0.f;
    if (s1) v1 = 0.f;
    if (lane == 0) {
      u64* p = (u64*)&xs_bits[((size_t)t * BB + b) * 4];
      p[0] = lo;
      p[1] = hi;
    }
  }
}

// ---------------- K2: W -> bf16 + per-branch global acc bounds (encoded atomics) -----
__global__ __launch_bounds__(256) void k_wconv(
    const float* __restrict__ Wq, const float* __restrict__ Wk, const float* __restrict__ Wv,
    const float* __restrict__ bq, const float* __restrict__ gq, const float* __restrict__ betq,
    const float* __restrict__ mq, const float* __restrict__ vq,
    const float* __restrict__ bk, const float* __restrict__ gk, const float* __restrict__ betk,
    const float* __restrict__ mk, const float* __restrict__ vk,
    const float* __restrict__ bv, const float* __restrict__ gv, const float* __restrict__ betv,
    const float* __restrict__ mv, const float* __restrict__ vv_,
    uint16_t* __restrict__ Wb, uint32_t* __restrict__ cbuf) {
  const int wv = threadIdx.x >> 6, lane = threadIdx.x & 63;
  const int row = blockIdx.x * 4 + wv;          // 0..3071
  const int br = row >> 10, dh = row & 1023;
  const float* W = (br == 0) ? Wq : (br == 1) ? Wk : Wv;
  float d = 0.f;
#pragma unroll
  for (int h = 0; h < 2; h++) {
    int k = lane + 64 * h;
    float w = W[(size_t)dh * DD + k];
    uint32_t bits = __builtin_bit_cast(uint32_t, w);
    uint32_t r = (bits + 0x7fffu + ((bits >> 16) & 1u)) >> 16;   // RNE to bf16
    Wb[(size_t)row * DD + k] = (uint16_t)r;
    d += fabsf(w - __builtin_bit_cast(float, r << 16));
  }
#pragma unroll
  for (int s2 = 1; s2 < 64; s2 <<= 1) d += __shfl_xor(d, s2);
  if (lane == 0) {
    const float* gg  = (br == 0) ? gq : (br == 1) ? gk : gv;
    const float* bb  = (br == 0) ? bq : (br == 1) ? bk : bv;
    const float* be  = (br == 0) ? betq : (br == 1) ? betk : betv;
    const float* mm  = (br == 0) ? mq : (br == 1) ? mk : mv;
    const float* vv2 = (br == 0) ? vq : (br == 1) ? vk : vv_;
    float sc = gg[dh] / sqrtf(vv2[dh] + 1e-5f);
    float c1 = (bb[dh] - mm[dh]) * sc + be[dh];
    float err = fabsf(sc) * d + 1e-3f;
    // no spike (u_t = conv-avg of y's, coeff sum <= 15/16) if ymax < 16/15 - err
    float B0 = 1.0666f - err;
    if (sc > 1e-20f) {
      atomicMin(&cbuf[br], encf((B0 - c1) / sc - 1e-4f));        // acc upper bound
    } else if (sc < -1e-20f) {
      atomicMax(&cbuf[3 + br], encf((B0 - c1) / sc + 1e-4f));    // acc lower bound
    } else if (c1 >= B0) {
      atomicMin(&cbuf[br], encf(-3.0e38f));                      // always flag
    }
  }
}

// ---------------- K3: MFMA certificate + fused fast-path output writes ---------------
// Grid (32 M-chunks, 16 N-tiles), 256 thr = 4 waves stacked in M.
// Per block: B (3 branches x 64 cols x 128 k) staged once in LDS; M-loop over 4x256
// rows; A fragments expanded from spike bits directly in registers (no LDS, no sync).
// Rows reordered m' = b*4 + t. Unconditionally streams v=0 and out=BN(bp)+x (the
// no-spike fast path); gated exact fallback overwrites if the certificate flags.
__global__ __launch_bounds__(256) void k_cert(
    const uint32_t* __restrict__ xs_bits,
    const uint16_t* __restrict__ Wb, const uint32_t* __restrict__ cbuf,
    const float* __restrict__ x,
    const float* __restrict__ bp, const float* __restrict__ gp,
    const float* __restrict__ betp, const float* __restrict__ mp,
    const float* __restrict__ vp,
    float* __restrict__ out, int* __restrict__ flag)
{
  __shared__ short Bs[3 * 64 * 128];   // 48 KB
  __shared__ float cold[128];

  const int tx = threadIdx.x;
  const int n0 = blockIdx.y * 64;
  const int lb = blockIdx.x * 16 + blockIdx.y;   // 0..511 linear block id
  const int lane = tx & 63, wm = tx >> 6;
  const int l15 = lane & 15, l4 = lane >> 4;

  // ---- stage B (swizzled slots: s' = s ^ (n&15)) + out BN constants ----
  {
    const uint4* Wb4 = (const uint4*)Wb;
#pragma unroll
    for (int i = 0; i < 12; i++) {
      int f = tx + i * 256;            // 0..3071 = 192 rows x 16 slots
      int row = f >> 4, s = f & 15;
      int br = row >> 6, n = row & 63;
      uint4 w = Wb4[((size_t)(br << 10) + n0 + n) * 16 + s];
      *(uint4*)&Bs[(br * 64 + n) * 128 + ((s ^ (n & 15)) << 3)] = w;
    }
    if (tx < 128) {
      float scp = gp[tx] / sqrtf(vp[tx] + 1e-5f);
      cold[tx] = __fadd_rn(__fmul_rn(__fsub_rn(bp[tx], mp[tx]), scp), betp[tx]);
    }
  }
  __syncthreads();

  // per-thread out columns are fixed: o&31 == tx&31
  float c4[4];
  {
    int c0 = (tx & 31) * 4;
#pragma unroll
    for (int c = 0; c < 4; c++) c4[c] = cold[c0 + c];
  }

  float hi[3], lo[3];
#pragma unroll
  for (int i = 0; i < 3; i++) { hi[i] = decf(cbuf[i]); lo[i] = decf(cbuf[3 + i]); }

  float mx[3] = {-3.0e38f, -3.0e38f, -3.0e38f};
  float mn[3] = { 3.0e38f,  3.0e38f,  3.0e38f};

  float* vout = out + ON;
  const float4 z4 = {0.f, 0.f, 0.f, 0.f};
  const int sh = l4 * 8;

  // prologue bits load (rows m' = b*4+t; lane&15 selects row within 16-row frag)
  uint4 bits[4];
  {
    int mrow = blockIdx.x * 1024 + wm * 64;
#pragma unroll
    for (int mf = 0; mf < 4; mf++) {
      int rp = mrow + mf * 16 + l15;
      bits[mf] = ((const uint4*)xs_bits)[(size_t)(rp & 3) * BB + (rp >> 2)];
    }
  }

  for (int it = 0; it < 4; it++) {
    // ---- expand A fragments in registers ----
    bf16x8 afr[4][4];
#pragma unroll
    for (int mf = 0; mf < 4; mf++) {
      uint32_t wk[4] = {bits[mf].x, bits[mf].y, bits[mf].z, bits[mf].w};
#pragma unroll
      for (int ks = 0; ks < 4; ks++) {
        uint32_t by = (wk[ks] >> sh) & 0xffu;
        bf16x8 v;
#pragma unroll
        for (int j = 0; j < 8; j++) v[j] = (by & (1u << j)) ? (short)0x3F80 : (short)0;
        afr[mf][ks] = v;
      }
    }
    // ---- prefetch next iter's bits ----
    if (it < 3) {
      int mrow = blockIdx.x * 1024 + (it + 1) * 256 + wm * 64;
#pragma unroll
      for (int mf = 0; mf < 4; mf++) {
        int rp = mrow + mf * 16 + l15;
        bits[mf] = ((const uint4*)xs_bits)[(size_t)(rp & 3) * BB + (rp >> 2)];
      }
    }

    // ---- fast-path output stores (overlap with MFMA): 16 v-zero + 2 out per iter ----
#pragma unroll
    for (int j = 0; j < 16; j++) {
      int idx = (it * 16 + j) * 131072 + lb * 256 + tx;   // < VN/4
      ((float4*)vout)[idx] = z4;
    }
#pragma unroll
    for (int j = 0; j < 2; j++) {
      int o = (it * 2 + j) * 131072 + lb * 256 + tx;      // < ON/4
      float4 xv = ((const float4*)x)[o];
      float4 r = {__fadd_rn(c4[0], xv.x), __fadd_rn(c4[1], xv.y),
                  __fadd_rn(c4[2], xv.z), __fadd_rn(c4[3], xv.w)};
      ((float4*)out)[o] = r;
    }

    // ---- 3 branches: 64 MFMA each, fold acc into running max/min ----
#pragma unroll
    for (int br = 0; br < 3; br++) {
      f32x4 acc[4][4];
#pragma unroll
      for (int mf = 0; mf < 4; mf++)
#pragma unroll
        for (int nf = 0; nf < 4; nf++) acc[mf][nf] = (f32x4){0.f, 0.f, 0.f, 0.f};

#pragma unroll
      for (int ks = 0; ks < 4; ks++) {
        int s = ks * 4 + l4;
#pragma unroll
        for (int nf = 0; nf < 4; nf++) {
          int n = nf * 16 + l15;
          bf16x8 bfr = *(const bf16x8*)&Bs[(br * 64 + n) * 128 + ((s ^ (n & 15)) << 3)];
#pragma unroll
          for (int mf = 0; mf < 4; mf++)
            acc[mf][nf] = __builtin_amdgcn_mfma_f32_16x16x32_bf16(afr[mf][ks], bfr,
                                                                  acc[mf][nf], 0, 0, 0);
        }
      }
      float m1 = mx[br], m2 = mn[br];
#pragma unroll
      for (int mf = 0; mf < 4; mf++)
#pragma unroll
        for (int nf = 0; nf < 4; nf++) {
          f32x4 a = acc[mf][nf];
          m1 = fmaxf(fmaxf(m1, fmaxf(a[0], a[1])), fmaxf(a[2], a[3]));
          m2 = fminf(fminf(m2, fminf(a[0], a[1])), fminf(a[2], a[3]));
        }
      mx[br] = m1; mn[br] = m2;
    }
  }

  bool bad = (mx[0] > hi[0]) || (mn[0] < lo[0]) ||
             (mx[1] > hi[1]) || (mn[1] < lo[1]) ||
             (mx[2] > hi[2]) || (mn[2] < lo[2]);
  if (__any((int)bad)) {
    if (lane == 0) atomicOr(flag, 1);
  }
}

// ---------------- Fallback (flag!=0): bit-exact sparse pipeline (unchanged, proven) --
__global__ __launch_bounds__(256) void k_qkv(
    const uint32_t* __restrict__ xs_bits,
    const float* __restrict__ Wq, const float* __restrict__ Wk, const float* __restrict__ Wv,
    const float* __restrict__ bq, const float* __restrict__ gq, const float* __restrict__ betq,
    const float* __restrict__ mq, const float* __restrict__ vq,
    const float* __restrict__ bk, const float* __restrict__ gk, const float* __restrict__ betk,
    const float* __restrict__ mk, const float* __restrict__ vk,
    const float* __restrict__ bv, const float* __restrict__ gv, const float* __restrict__ betv,
    const float* __restrict__ mv, const float* __restrict__ vv_,
    float* __restrict__ vout, uint8_t* __restrict__ a_bytes,
    const int* __restrict__ flag)
{
  if (flag[0] == 0) return;
  __shared__ float W_s[128 * 64];

  const int tx = threadIdx.x;
  const int b0 = blockIdx.x * 64;
  const int dh0 = blockIdx.y * 64;
  const int lane = tx & 63;
  const int grp = tx >> 6;
  const int dh = dh0 + lane;

  auto lds_w = [&](int kk) -> float {
    return W_s[(kk << 6) | (lane ^ (kk >> 2))];
  };
  auto scan = [&](u64 m, int base, float a) -> float {
    if (m) {
      int k = __builtin_ctzll(m); m &= m - 1;
      float wv = lds_w(base + k);
      while (m) {
        int k2 = __builtin_ctzll(m); m &= m - 1;
        float wn = lds_w(base + k2);
        a = __fadd_rn(a, wv);
        wv = wn;
      }
      a = __fadd_rn(a, wv);
    }
    return a;
  };

  auto branch = [&](const float* __restrict__ Wg, const float* __restrict__ bb,
                    const float* __restrict__ gg, const float* __restrict__ be,
                    const float* __restrict__ mmp, const float* __restrict__ vvp) -> u64 {
    __syncthreads();
    {
      const float4* Wg4 = (const float4*)(Wg + (size_t)dh0 * DD);
#pragma unroll
      for (int j = 0; j < 8; j++) {
        int idx = tx + j * 256;
        int n = idx >> 5, k4 = idx & 31;
        float4 w = Wg4[n * 32 + k4];
        int kk = k4 * 4;
        int col = n ^ k4;
        W_s[(kk + 0) * 64 + col] = w.x;
        W_s[(kk + 1) * 64 + col] = w.y;
        W_s[(kk + 2) * 64 + col] = w.z;
        W_s[(kk + 3) * 64 + col] = w.w;
      }
    }
    __syncthreads();

    float acc[TT][16];
#pragma unroll
    for (int t = 0; t < TT; t++)
#pragma unroll
      for (int bi = 0; bi < 16; bi++) acc[t][bi] = 0.f;

    const uint4* xb = (const uint4*)xs_bits;
#pragma unroll
    for (int bi = 0; bi < 16; bi++) {
      const int b = b0 + grp * 16 + bi;
#pragma unroll
      for (int t = 0; t < TT; t++) {
        uint4 m4 = xb[(size_t)t * BB + b];
        u64 mlo = ((u64)(uint32_t)__builtin_amdgcn_readfirstlane(m4.y) << 32) |
                  (uint32_t)__builtin_amdgcn_readfirstlane(m4.x);
        u64 mhi = ((u64)(uint32_t)__builtin_amdgcn_readfirstlane(m4.w) << 32) |
                  (uint32_t)__builtin_amdgcn_readfirstlane(m4.z);
        float a = acc[t][bi];
        a = scan(mlo, 0, a);
        a = scan(mhi, 64, a);
        acc[t][bi] = a;
      }
    }

    float bias = bb[dh];
    float sc = gg[dh] / sqrtf(vvp[dh] + 1e-5f);
    float mmv = mmp[dh];
    float bev = be[dh];
    u64 bits = 0;
#pragma unroll
    for (int bi = 0; bi < 16; bi++) {
      float u = 0.f;
#pragma unroll
      for (int t = 0; t < TT; t++) {
        float y = __fadd_rn(acc[t][bi], bias);
        y = __fadd_rn(__fmul_rn(__fsub_rn(y, mmv), sc), bev);
        u = __fadd_rn(u, __fmul_rn(__fsub_rn(y, u), 0.5f));
        if (u >= 1.0f) { bits |= (1ull << (t * 16 + bi)); u = 0.f; }
      }
    }
    return bits;
  };

  u64 qb = branch(Wq, bq, gq, betq, mq, vq);
  u64 kb = branch(Wk, bk, gk, betk, mk, vk);
  u64 vb = branch(Wv, bv, gv, betv, mv, vv_);

  const int hh2 = lane & 7;
  const int dg = (dh0 >> 3) + (lane >> 3);
#pragma unroll
  for (int t = 0; t < TT; t++) {
#pragma unroll
    for (int bi = 0; bi < 16; bi++) {
      float s = (float)((vb >> (t * 16 + bi)) & 1ull);
      vout[(((size_t)t * BB + (b0 + grp * 16 + bi)) * HH + hh2) * DD + dg] = s;
    }
  }

  u64 kvand = kb & vb;
  u64 ab = 0;
#pragma unroll
  for (int bi = 0; bi < 16; bi++) {
    float u = 0.f;
#pragma unroll
    for (int t = 0; t < TT; t++) {
      float kvf = (float)((kvand >> (t * 16 + bi)) & 1ull);
      kvf += __shfl_xor(kvf, 1);
      kvf += __shfl_xor(kvf, 2);
      kvf += __shfl_xor(kvf, 4);
      u = u + (kvf - u) * 0.5f;
      uint32_t s = (u >= 0.5f) ? 1u : 0u;
      if (s) u = 0.f;
      uint32_t qbit = (uint32_t)((qb >> (t * 16 + bi)) & 1ull);
      ab |= (u64)(qbit & s) << (t * 16 + bi);
    }
  }

#pragma unroll
  for (int t = 0; t < TT; t++) {
#pragma unroll
    for (int bi = 0; bi < 16; bi++) {
      u64 msk = __ballot((int)((ab >> (t * 16 + bi)) & 1ull));
      if (lane < 8) {
        uint32_t byte = 0;
#pragma unroll
        for (int d2 = 0; d2 < 8; d2++)
          byte |= (uint32_t)((msk >> (d2 * 8 + lane)) & 1ull) << d2;
        a_bytes[((size_t)t * BB + (b0 + grp * 16 + bi)) * 128 + lane * 16 + blockIdx.y] =
            (uint8_t)byte;
      }
    }
  }
}

__global__ __launch_bounds__(256) void k_out(
    const uint8_t* __restrict__ a_bytes,
    const float* __restrict__ Wp, const float* __restrict__ bp2,
    const float* __restrict__ gp, const float* __restrict__ betp,
    const float* __restrict__ mp, const float* __restrict__ vp,
    const float* __restrict__ x, float* __restrict__ out,
    const int* __restrict__ flag)
{
  if (flag[0] == 0) return;
  const int wv = threadIdx.x >> 6, lane = threadIdx.x & 63;
  const size_t m = (size_t)blockIdx.x * 4 + wv;

  const uint4* aw = (const uint4*)(a_bytes + m * 128);
  float acc0 = 0.f, acc1 = 0.f;
#pragma unroll
  for (int q4 = 0; q4 < 8; q4++) {
    uint4 mq = aw[q4];
    uint32_t ws[4];
    ws[0] = (uint32_t)__builtin_amdgcn_readfirstlane(mq.x);
    ws[1] = (uint32_t)__builtin_amdgcn_readfirstlane(mq.y);
    ws[2] = (uint32_t)__builtin_amdgcn_readfirstlane(mq.z);
    ws[3] = (uint32_t)__builtin_amdgcn_readfirstlane(mq.w);
#pragma unroll
    for (int w = 0; w < 4; w++) {
      uint32_t mm = ws[w];
      while (mm) {
        int kb = __builtin_ctz(mm); mm &= mm - 1;
        int k = q4 * 128 + w * 32 + kb;
        acc0 = __fadd_rn(acc0, Wp[(size_t)lane * DHD + k]);
        acc1 = __fadd_rn(acc1, Wp[(size_t)(lane + 64) * DHD + k]);
      }
    }
  }

#pragma unroll
  for (int half = 0; half < 2; half++) {
    int j = lane + half * 64;
    float acc = half ? acc1 : acc0;
    float scp = gp[j] / sqrtf(vp[j] + 1e-5f);
    float y = __fadd_rn(acc, bp2[j]);
    y = __fadd_rn(__fmul_rn(__fsub_rn(y, mp[j]), scp), betp[j]);
    y = __fadd_rn(y, x[m * DD + j]);
    out[m * DD + j] = y;
  }
}

// ---------------- launch ----------------
extern "C" void kernel_launch(void* const* d_in, const int* in_sizes, int n_in,
                              void* d_out, int out_size, void* d_ws, size_t ws_size,
                              hipStream_t stream) {
  const float* x    = (const float*)d_in[0];
  const float* Wq   = (const float*)d_in[1];
  const float* Wk   = (const float*)d_in[2];
  const float* Wv   = (const float*)d_in[3];
  const float* Wp   = (const float*)d_in[4];
  const float* bq   = (const float*)d_in[5];
  const float* gq   = (const float*)d_in[6];
  const float* betq = (const float*)d_in[7];
  const float* mq   = (const float*)d_in[8];
  const float* vq   = (const float*)d_in[9];
  const float* bk   = (const float*)d_in[10];
  const float* gk   = (const float*)d_in[11];
  const float* betk = (const float*)d_in[12];
  const float* mk   = (const float*)d_in[13];
  const float* vk   = (const float*)d_in[14];
  const float* bv   = (const float*)d_in[15];
  const float* gv   = (const float*)d_in[16];
  const float* betv = (const float*)d_in[17];
  const float* mv   = (const float*)d_in[18];
  const float* vv   = (const float*)d_in[19];
  const float* bp   = (const float*)d_in[20];
  const float* gp   = (const float*)d_in[21];
  const float* betp = (const float*)d_in[22];
  const float* mp   = (const float*)d_in[23];
  const float* vp   = (const float*)d_in[24];

  float* out  = (float*)d_out;
  float* vout = out + (size_t)ON;

  uint8_t* ws = (uint8_t*)d_ws;
  uint32_t* xs_bits = (uint32_t*)ws;                        // 512 KB
  uint8_t*  a_bytes = ws + 524288;                          // 4 MB
  uint16_t* Wb      = (uint16_t*)(ws + 4718592);            // 768 KB
  uint32_t* cbuf    = (uint32_t*)(ws + 5505024);            // 24 B
  int*      flag    = (int*)(ws + 5505056);                 // 4 B

  k_lif_x<<<BB / 4, 256, 0, stream>>>(x, xs_bits, flag, cbuf);

  k_wconv<<<768, 256, 0, stream>>>(Wq, Wk, Wv,
                                   bq, gq, betq, mq, vq,
                                   bk, gk, betk, mk, vk,
                                   bv, gv, betv, mv, vv,
                                   Wb, cbuf);

  dim3 gc(32, 16);
  k_cert<<<gc, 256, 0, stream>>>(xs_bits, Wb, cbuf, x, bp, gp, betp, mp, vp, out, flag);

  dim3 g2(BB / 64, DHD / 64);
  k_qkv<<<g2, 256, 0, stream>>>(xs_bits, Wq, Wk, Wv,
                                bq, gq, betq, mq, vq,
                                bk, gk, betk, mk, vk,
                                bv, gv, betv, mv, vv,
                                vout, a_bytes, flag);

  k_out<<<TBM / 4, 256, 0, stream>>>(a_bytes, Wp, bp, gp, betp, mp, vp, x, out, flag);
}

// Round 5
// 64.463 us; speedup vs baseline: 18.9697x; 1.4450x over previous
//
#include <hip/hip_runtime.h>
#include <stdint.h>

#define TT 4
#define BB 8192
#define DD 128
#define HH 8
#define DHD 1024
#define BD (BB*DD)       // 1048576
#define TBM (TT*BB)      // 32768
#define VN (TT*BB*HH*DD) // 33554432
#define ON (TT*BB*DD)    // 4194304

typedef unsigned long long u64;
typedef __attribute__((ext_vector_type(8))) short bf16x8;
typedef __attribute__((ext_vector_type(4))) float f32x4;

// ---------------- K1: fused pre-kernel -----------------------------------------------
// Blocks [0,2048): shortcut LIF -> bit-packed spike masks + fast-path out = BN(bp)+x
//   (x is read exactly once; out overwritten later by fallback iff flag fires).
// Blocks [2048,2816): W -> bf16 (RNE) + per-row no-spike acc bounds hb/lb (plain
//   stores, no atomics -> no init-order hazard).
__global__ __launch_bounds__(256) void k_pre(
    const float* __restrict__ x,
    const float* __restrict__ Wq, const float* __restrict__ Wk, const float* __restrict__ Wv,
    const float* __restrict__ bq, const float* __restrict__ gq, const float* __restrict__ betq,
    const float* __restrict__ mq, const float* __restrict__ vq,
    const float* __restrict__ bk, const float* __restrict__ gk, const float* __restrict__ betk,
    const float* __restrict__ mk, const float* __restrict__ vk,
    const float* __restrict__ bv, const float* __restrict__ gv, const float* __restrict__ betv,
    const float* __restrict__ mv, const float* __restrict__ vv_,
    const float* __restrict__ bp, const float* __restrict__ gp,
    const float* __restrict__ betp, const float* __restrict__ mp,
    const float* __restrict__ vp,
    uint32_t* __restrict__ xs_bits, float* __restrict__ out,
    uint16_t* __restrict__ Wb, float* __restrict__ hb, float* __restrict__ lbd,
    int* __restrict__ flag)
{
  const int wv = threadIdx.x >> 6, lane = threadIdx.x & 63;
  if (blockIdx.x == 0 && threadIdx.x == 0) *flag = 0;

  if (blockIdx.x < 2048) {
    // ---- LIF over x + fast-path out ----
    const int b = blockIdx.x * 4 + wv;
    const int d0 = lane, d1 = lane + 64;
    float s0 = gp[d0] / sqrtf(vp[d0] + 1e-5f);
    float c0 = __fadd_rn(__fmul_rn(__fsub_rn(bp[d0], mp[d0]), s0), betp[d0]);
    float s1 = gp[d1] / sqrtf(vp[d1] + 1e-5f);
    float c1 = __fadd_rn(__fmul_rn(__fsub_rn(bp[d1], mp[d1]), s1), betp[d1]);

    float v0 = 0.f, v1 = 0.f;
#pragma unroll
    for (int t = 0; t < TT; t++) {
      size_t base = (size_t)t * BD + (size_t)b * DD;
      float x0 = x[base + d0];
      float x1 = x[base + d1];
      out[base + d0] = __fadd_rn(c0, x0);       // same op order as R4 (proven exact)
      out[base + d1] = __fadd_rn(c1, x1);
      v0 = __fadd_rn(v0, __fmul_rn(__fsub_rn(x0, v0), 0.5f));
      v1 = __fadd_rn(v1, __fmul_rn(__fsub_rn(x1, v1), 0.5f));
      int sp0 = (v0 >= 1.0f) ? 1 : 0;
      int sp1 = (v1 >= 1.0f) ? 1 : 0;
      u64 lo = __ballot(sp0);
      u64 hi = __ballot(sp1);
      if (sp0) v0 = 0.f;
      if (sp1) v1 = 0.f;
      if (lane == 0) {
        u64* p = (u64*)&xs_bits[((size_t)t * BB + b) * 4];
        p[0] = lo;
        p[1] = hi;
      }
    }
  } else {
    // ---- W -> bf16 + per-row bounds ----
    const int row = (blockIdx.x - 2048) * 4 + wv;     // 0..3071
    const int br = row >> 10, dh = row & 1023;
    const float* W = (br == 0) ? Wq : (br == 1) ? Wk : Wv;
    float d = 0.f;
#pragma unroll
    for (int h = 0; h < 2; h++) {
      int k = lane + 64 * h;
      float w = W[(size_t)dh * DD + k];
      uint32_t bits = __builtin_bit_cast(uint32_t, w);
      uint32_t r = (bits + 0x7fffu + ((bits >> 16) & 1u)) >> 16;   // RNE to bf16
      Wb[(size_t)row * DD + k] = (uint16_t)r;
      d += fabsf(w - __builtin_bit_cast(float, r << 16));
    }
#pragma unroll
    for (int s2 = 1; s2 < 64; s2 <<= 1) d += __shfl_xor(d, s2);
    if (lane == 0) {
      const float* gg  = (br == 0) ? gq : (br == 1) ? gk : gv;
      const float* bb  = (br == 0) ? bq : (br == 1) ? bk : bv;
      const float* be  = (br == 0) ? betq : (br == 1) ? betk : betv;
      const float* mm  = (br == 0) ? mq : (br == 1) ? mk : mv;
      const float* vv2 = (br == 0) ? vq : (br == 1) ? vk : vv_;
      float sc = gg[dh] / sqrtf(vv2[dh] + 1e-5f);
      float c1 = (bb[dh] - mm[dh]) * sc + be[dh];
      float err = fabsf(sc) * d + 1e-3f;
      // no spike iff ymax < 16/15 - err  (u_t = conv avg, coeff sum <= 15/16)
      float B0 = 1.0666f - err;
      float h = 3.0e38f, l = -3.0e38f;
      if (sc > 1e-20f) {
        h = (B0 - c1) / sc - 1e-4f;                  // acc upper bound
      } else if (sc < -1e-20f) {
        l = (B0 - c1) / sc + 1e-4f;                  // acc lower bound
      } else if (c1 >= B0) {
        h = -3.0e38f;                                // always flag
      }
      hb[row] = h;
      lbd[row] = l;
    }
  }
}

// ---------------- K2: MFMA certificate + fused v-zero stream -------------------------
// Grid (64 M-chunks, 32 N-tiles) = 2048 blocks, 256 thr = 4 waves stacked in M.
// B tile (3 br x 32 cols x 128 k bf16, 24 KB LDS, XOR-swizzled slots) staged once;
// A fragments expanded from spike bits in registers (no LDS, no barriers in M-loop).
// Per-block bounds = reduce of per-row hb/lb over its own 32 columns (layout-
// agnostic: max/min of acc tile vs min/max of column bounds). Streams v=0
// unconditionally; gated exact fallback overwrites everything if flagged.
__global__ __launch_bounds__(256) void k_cert(
    const uint32_t* __restrict__ xs_bits,
    const uint16_t* __restrict__ Wb,
    const float* __restrict__ hb, const float* __restrict__ lbd,
    float* __restrict__ vout, int* __restrict__ flag)
{
  __shared__ short Bs[3 * 32 * 128];   // 24 KB

  const int tx = threadIdx.x;
  const int n0 = blockIdx.y * 32;
  const int lb = blockIdx.x * 32 + blockIdx.y;   // 0..2047
  const int lane = tx & 63, wm = tx >> 6;
  const int l15 = lane & 15, l4 = lane >> 4;
  const int sh = l4 * 8;

  // ---- stage B (swizzled slots: s' = s ^ (n&15)) ----
  {
    const uint4* Wb4 = (const uint4*)Wb;
#pragma unroll
    for (int i = 0; i < 6; i++) {
      int f = tx + i * 256;            // 0..1535 = 96 rows x 16 slots
      int row = f >> 4, s = f & 15;
      int br = row >> 5, n = row & 31;
      uint4 w = Wb4[((size_t)(br << 10) + n0 + n) * 16 + s];
      *(uint4*)&Bs[(br * 32 + n) * 128 + ((s ^ (n & 15)) << 3)] = w;
    }
  }

  // ---- per-block bounds: min/max over this tile's 32 columns ----
  float hi[3], lo[3];
#pragma unroll
  for (int br = 0; br < 3; br++) {
    float h = hb[br * 1024 + n0 + (lane & 31)];
    float l = lbd[br * 1024 + n0 + (lane & 31)];
#pragma unroll
    for (int s2 = 1; s2 < 32; s2 <<= 1) {
      h = fminf(h, __shfl_xor(h, s2));
      l = fmaxf(l, __shfl_xor(l, s2));
    }
    hi[br] = h; lo[br] = l;
  }

  float mx[3] = {-3.0e38f, -3.0e38f, -3.0e38f};
  float mn[3] = { 3.0e38f,  3.0e38f,  3.0e38f};
  const float4 z4 = {0.f, 0.f, 0.f, 0.f};

  // prologue bits load (rows m' = b*4+t)
  uint4 bits[4];
  {
    int mrow = blockIdx.x * 512 + wm * 64;
#pragma unroll
    for (int mf = 0; mf < 4; mf++) {
      int rp = mrow + mf * 16 + l15;
      bits[mf] = ((const uint4*)xs_bits)[(size_t)(rp & 3) * BB + (rp >> 2)];
    }
  }
  __syncthreads();

  for (int it = 0; it < 2; it++) {
    // ---- expand A fragments in registers ----
    bf16x8 afr[4][4];
#pragma unroll
    for (int mf = 0; mf < 4; mf++) {
      uint32_t wk[4] = {bits[mf].x, bits[mf].y, bits[mf].z, bits[mf].w};
#pragma unroll
      for (int ks = 0; ks < 4; ks++) {
        uint32_t by = (wk[ks] >> sh) & 0xffu;
        bf16x8 v;
#pragma unroll
        for (int j = 0; j < 8; j++) v[j] = (by & (1u << j)) ? (short)0x3F80 : (short)0;
        afr[mf][ks] = v;
      }
    }
    if (it == 0) {
      int mrow = blockIdx.x * 512 + 256 + wm * 64;
#pragma unroll
      for (int mf = 0; mf < 4; mf++) {
        int rp = mrow + mf * 16 + l15;
        bits[mf] = ((const uint4*)xs_bits)[(size_t)(rp & 3) * BB + (rp >> 2)];
      }
    }

    // ---- v-zero stores, overlapped with MFMA ----
#pragma unroll
    for (int j = 0; j < 8; j++) {
      int idx = (it * 8 + j) * 524288 + lb * 256 + tx;   // covers VN/4 exactly
      ((float4*)vout)[idx] = z4;
    }

    // ---- 3 branches x 32 MFMA, fold into running max/min ----
#pragma unroll
    for (int br = 0; br < 3; br++) {
      f32x4 acc[4][2];
#pragma unroll
      for (int mf = 0; mf < 4; mf++)
#pragma unroll
        for (int nf = 0; nf < 2; nf++) acc[mf][nf] = (f32x4){0.f, 0.f, 0.f, 0.f};

#pragma unroll
      for (int ks = 0; ks < 4; ks++) {
        int s = ks * 4 + l4;
#pragma unroll
        for (int nf = 0; nf < 2; nf++) {
          int n = nf * 16 + l15;
          bf16x8 bfr = *(const bf16x8*)&Bs[(br * 32 + n) * 128 + ((s ^ (n & 15)) << 3)];
#pragma unroll
          for (int mf = 0; mf < 4; mf++)
            acc[mf][nf] = __builtin_amdgcn_mfma_f32_16x16x32_bf16(afr[mf][ks], bfr,
                                                                  acc[mf][nf], 0, 0, 0);
        }
      }
      float m1 = mx[br], m2 = mn[br];
#pragma unroll
      for (int mf = 0; mf < 4; mf++)
#pragma unroll
        for (int nf = 0; nf < 2; nf++) {
          f32x4 a = acc[mf][nf];
          m1 = fmaxf(fmaxf(m1, fmaxf(a[0], a[1])), fmaxf(a[2], a[3]));
          m2 = fminf(fminf(m2, fminf(a[0], a[1])), fminf(a[2], a[3]));
        }
      mx[br] = m1; mn[br] = m2;
    }
  }

  bool bad = (mx[0] > hi[0]) || (mn[0] < lo[0]) ||
             (mx[1] > hi[1]) || (mn[1] < lo[1]) ||
             (mx[2] > hi[2]) || (mn[2] < lo[2]);
  if (__any((int)bad)) {
    if (lane == 0) atomicOr(flag, 1);
  }
}

// ---------------- Fallback (flag!=0): bit-exact sparse pipeline (unchanged, proven) --
__global__ __launch_bounds__(256) void k_qkv(
    const uint32_t* __restrict__ xs_bits,
    const float* __restrict__ Wq, const float* __restrict__ Wk, const float* __restrict__ Wv,
    const float* __restrict__ bq, const float* __restrict__ gq, const float* __restrict__ betq,
    const float* __restrict__ mq, const float* __restrict__ vq,
    const float* __restrict__ bk, const float* __restrict__ gk, const float* __restrict__ betk,
    const float* __restrict__ mk, const float* __restrict__ vk,
    const float* __restrict__ bv, const float* __restrict__ gv, const float* __restrict__ betv,
    const float* __restrict__ mv, const float* __restrict__ vv_,
    float* __restrict__ vout, uint8_t* __restrict__ a_bytes,
    const int* __restrict__ flag)
{
  if (flag[0] == 0) return;
  __shared__ float W_s[128 * 64];

  const int tx = threadIdx.x;
  const int b0 = blockIdx.x * 64;
  const int dh0 = blockIdx.y * 64;
  const int lane = tx & 63;
  const int grp = tx >> 6;
  const int dh = dh0 + lane;

  auto lds_w = [&](int kk) -> float {
    return W_s[(kk << 6) | (lane ^ (kk >> 2))];
  };
  auto scan = [&](u64 m, int base, float a) -> float {
    if (m) {
      int k = __builtin_ctzll(m); m &= m - 1;
      float wv = lds_w(base + k);
      while (m) {
        int k2 = __builtin_ctzll(m); m &= m - 1;
        float wn = lds_w(base + k2);
        a = __fadd_rn(a, wv);
        wv = wn;
      }
      a = __fadd_rn(a, wv);
    }
    return a;
  };

  auto branch = [&](const float* __restrict__ Wg, const float* __restrict__ bb,
                    const float* __restrict__ gg, const float* __restrict__ be,
                    const float* __restrict__ mmp, const float* __restrict__ vvp) -> u64 {
    __syncthreads();
    {
      const float4* Wg4 = (const float4*)(Wg + (size_t)dh0 * DD);
#pragma unroll
      for (int j = 0; j < 8; j++) {
        int idx = tx + j * 256;
        int n = idx >> 5, k4 = idx & 31;
        float4 w = Wg4[n * 32 + k4];
        int kk = k4 * 4;
        int col = n ^ k4;
        W_s[(kk + 0) * 64 + col] = w.x;
        W_s[(kk + 1) * 64 + col] = w.y;
        W_s[(kk + 2) * 64 + col] = w.z;
        W_s[(kk + 3) * 64 + col] = w.w;
      }
    }
    __syncthreads();

    float acc[TT][16];
#pragma unroll
    for (int t = 0; t < TT; t++)
#pragma unroll
      for (int bi = 0; bi < 16; bi++) acc[t][bi] = 0.f;

    const uint4* xb = (const uint4*)xs_bits;
#pragma unroll
    for (int bi = 0; bi < 16; bi++) {
      const int b = b0 + grp * 16 + bi;
#pragma unroll
      for (int t = 0; t < TT; t++) {
        uint4 m4 = xb[(size_t)t * BB + b];
        u64 mlo = ((u64)(uint32_t)__builtin_amdgcn_readfirstlane(m4.y) << 32) |
                  (uint32_t)__builtin_amdgcn_readfirstlane(m4.x);
        u64 mhi = ((u64)(uint32_t)__builtin_amdgcn_readfirstlane(m4.w) << 32) |
                  (uint32_t)__builtin_amdgcn_readfirstlane(m4.z);
        float a = acc[t][bi];
        a = scan(mlo, 0, a);
        a = scan(mhi, 64, a);
        acc[t][bi] = a;
      }
    }

    float bias = bb[dh];
    float sc = gg[dh] / sqrtf(vvp[dh] + 1e-5f);
    float mmv = mmp[dh];
    float bev = be[dh];
    u64 bits = 0;
#pragma unroll
    for (int bi = 0; bi < 16; bi++) {
      float u = 0.f;
#pragma unroll
      for (int t = 0; t < TT; t++) {
        float y = __fadd_rn(acc[t][bi], bias);
        y = __fadd_rn(__fmul_rn(__fsub_rn(y, mmv), sc), bev);
        u = __fadd_rn(u, __fmul_rn(__fsub_rn(y, u), 0.5f));
        if (u >= 1.0f) { bits |= (1ull << (t * 16 + bi)); u = 0.f; }
      }
    }
    return bits;
  };

  u64 qb = branch(Wq, bq, gq, betq, mq, vq);
  u64 kb = branch(Wk, bk, gk, betk, mk, vk);
  u64 vb = branch(Wv, bv, gv, betv, mv, vv_);

  const int hh2 = lane & 7;
  const int dg = (dh0 >> 3) + (lane >> 3);
#pragma unroll
  for (int t = 0; t < TT; t++) {
#pragma unroll
    for (int bi = 0; bi < 16; bi++) {
      float s = (float)((vb >> (t * 16 + bi)) & 1ull);
      vout[(((size_t)t * BB + (b0 + grp * 16 + bi)) * HH + hh2) * DD + dg] = s;
    }
  }

  u64 kvand = kb & vb;
  u64 ab = 0;
#pragma unroll
  for (int bi = 0; bi < 16; bi++) {
    float u = 0.f;
#pragma unroll
    for (int t = 0; t < TT; t++) {
      float kvf = (float)((kvand >> (t * 16 + bi)) & 1ull);
      kvf += __shfl_xor(kvf, 1);
      kvf += __shfl_xor(kvf, 2);
      kvf += __shfl_xor(kvf, 4);
      u = u + (kvf - u) * 0.5f;
      uint32_t s = (u >= 0.5f) ? 1u : 0u;
      if (s) u = 0.f;
      uint32_t qbit = (uint32_t)((qb >> (t * 16 + bi)) & 1ull);
      ab |= (u64)(qbit & s) << (t * 16 + bi);
    }
  }

#pragma unroll
  for (int t = 0; t < TT; t++) {
#pragma unroll
    for (int bi = 0; bi < 16; bi++) {
      u64 msk = __ballot((int)((ab >> (t * 16 + bi)) & 1ull));
      if (lane < 8) {
        uint32_t byte = 0;
#pragma unroll
        for (int d2 = 0; d2 < 8; d2++)
          byte |= (uint32_t)((msk >> (d2 * 8 + lane)) & 1ull) << d2;
        a_bytes[((size_t)t * BB + (b0 + grp * 16 + bi)) * 128 + lane * 16 + blockIdx.y] =
            (uint8_t)byte;
      }
    }
  }
}

__global__ __launch_bounds__(256) void k_out(
    const uint8_t* __restrict__ a_bytes,
    const float* __restrict__ Wp, const float* __restrict__ bp2,
    const float* __restrict__ gp, const float* __restrict__ betp,
    const float* __restrict__ mp, const float* __restrict__ vp,
    const float* __restrict__ x, float* __restrict__ out,
    const int* __restrict__ flag)
{
  if (flag[0] == 0) return;
  const int wv = threadIdx.x >> 6, lane = threadIdx.x & 63;
  const size_t m = (size_t)blockIdx.x * 4 + wv;

  const uint4* aw = (const uint4*)(a_bytes + m * 128);
  float acc0 = 0.f, acc1 = 0.f;
#pragma unroll
  for (int q4 = 0; q4 < 8; q4++) {
    uint4 mq = aw[q4];
    uint32_t ws[4];
    ws[0] = (uint32_t)__builtin_amdgcn_readfirstlane(mq.x);
    ws[1] = (uint32_t)__builtin_amdgcn_readfirstlane(mq.y);
    ws[2] = (uint32_t)__builtin_amdgcn_readfirstlane(mq.z);
    ws[3] = (uint32_t)__builtin_amdgcn_readfirstlane(mq.w);
#pragma unroll
    for (int w = 0; w < 4; w++) {
      uint32_t mm = ws[w];
      while (mm) {
        int kb = __builtin_ctz(mm); mm &= mm - 1;
        int k = q4 * 128 + w * 32 + kb;
        acc0 = __fadd_rn(acc0, Wp[(size_t)lane * DHD + k]);
        acc1 = __fadd_rn(acc1, Wp[(size_t)(lane + 64) * DHD + k]);
      }
    }
  }

#pragma unroll
  for (int half = 0; half < 2; half++) {
    int j = lane + half * 64;
    float acc = half ? acc1 : acc0;
    float scp = gp[j] / sqrtf(vp[j] + 1e-5f);
    float y = __fadd_rn(acc, bp2[j]);
    y = __fadd_rn(__fmul_rn(__fsub_rn(y, mp[j]), scp), betp[j]);
    y = __fadd_rn(y, x[m * DD + j]);
    out[m * DD + j] = y;
  }
}

// ---------------- launch ----------------
extern "C" void kernel_launch(void* const* d_in, const int* in_sizes, int n_in,
                              void* d_out, int out_size, void* d_ws, size_t ws_size,
                              hipStream_t stream) {
  const float* x    = (const float*)d_in[0];
  const float* Wq   = (const float*)d_in[1];
  const float* Wk   = (const float*)d_in[2];
  const float* Wv   = (const float*)d_in[3];
  const float* Wp   = (const float*)d_in[4];
  const float* bq   = (const float*)d_in[5];
  const float* gq   = (const float*)d_in[6];
  const float* betq = (const float*)d_in[7];
  const float* mq   = (const float*)d_in[8];
  const float* vq   = (const float*)d_in[9];
  const float* bk   = (const float*)d_in[10];
  const float* gk   = (const float*)d_in[11];
  const float* betk = (const float*)d_in[12];
  const float* mk   = (const float*)d_in[13];
  const float* vk   = (const float*)d_in[14];
  const float* bv   = (const float*)d_in[15];
  const float* gv   = (const float*)d_in[16];
  const float* betv = (const float*)d_in[17];
  const float* mv   = (const float*)d_in[18];
  const float* vv   = (const float*)d_in[19];
  const float* bp   = (const float*)d_in[20];
  const float* gp   = (const float*)d_in[21];
  const float* betp = (const float*)d_in[22];
  const float* mp   = (const float*)d_in[23];
  const float* vp   = (const float*)d_in[24];

  float* out  = (float*)d_out;
  float* vout = out + (size_t)ON;

  uint8_t* ws = (uint8_t*)d_ws;
  uint32_t* xs_bits = (uint32_t*)ws;                        // 512 KB
  uint8_t*  a_bytes = ws + 524288;                          // 4 MB
  uint16_t* Wb      = (uint16_t*)(ws + 4718592);            // 768 KB
  float*    hb      = (float*)(ws + 5505024);               // 12 KB
  float*    lbd     = (float*)(ws + 5517312);               // 12 KB
  int*      flag    = (int*)(ws + 5529600);                 // 4 B

  k_pre<<<2816, 256, 0, stream>>>(x, Wq, Wk, Wv,
                                  bq, gq, betq, mq, vq,
                                  bk, gk, betk, mk, vk,
                                  bv, gv, betv, mv, vv,
                                  bp, gp, betp, mp, vp,
                                  xs_bits, out, Wb, hb, lbd, flag);

  dim3 gc(64, 32);
  k_cert<<<gc, 256, 0, stream>>>(xs_bits, Wb, hb, lbd, vout, flag);

  dim3 g2(BB / 64, DHD / 64);
  k_qkv<<<g2, 256, 0, stream>>>(xs_bits, Wq, Wk, Wv,
                                bq, gq, betq, mq, vq,
                                bk, gk, betk, mk, vk,
                                bv, gv, betv, mv, vv,
                                vout, a_bytes, flag);

  k_out<<<TBM / 4, 256, 0, stream>>>(a_bytes, Wp, bp, gp, betp, mp, vp, x, out, flag);
}